// Round 2
// baseline (1758.676 us; speedup 1.0000x reference)
//
#include <hip/hip_runtime.h>

// RNNBlock: h_t = relu(x_t @ W + h_{t-1} @ U + b) over reversed T, then
// out = relu(h @ W1 + b1).  B=65536, T=79, F=8, C=DW=256.
//
// R2 design: block = 512 threads (8 waves), 64 batch rows. Each wave owns 32
// output channels: bf[17] half8 = 68 VGPRs (K augmented to 272 = 256 h + 8 x
// + 1 bias + 7 zero), acc = 2x f32x16 (32 regs), total ~125 -> fits 128-reg
// budget at __launch_bounds__(512,4) => 2 blocks/CU = 16 waves/CU (4/SIMD).
// R1 post-mortem: 136-reg bf[17][2] spilled ~8 dwords/step (FETCH/WRITE each
// ~+300MB of scratch) and 2 waves/SIMD couldn't hide the latency.
//
// h exchange: double-buffered LDS fp16 (2 x 32 KB), 16-byte-granule XOR
// swizzle so each A-fragment is ONE ds_read_b128 (conflict-free: granule
// index XORed with row spreads banks; verified <=2-way everywhere).
//
// MFMA v_mfma_f32_32x32x16_f16 layouts (learn_hip verified):
//   A[m][k]: m = lane&31, k = 8*(lane>>5) + j
//   B[k][n]: k = 8*(lane>>5) + j, n = lane&31
//   C/D    : col = lane&31, row = (reg&3) + 8*(reg>>2) + 4*(lane>>5)

#define B_ROWS 65536
#define T_STEPS 79
#define F_IN 8
#define C_DIM 256

typedef _Float16 h16;
typedef __attribute__((ext_vector_type(8))) _Float16 half8;
typedef __attribute__((ext_vector_type(16))) float f32x16;
typedef __attribute__((ext_vector_type(4))) float f32x4;

// LDS element index for h[r][c] (fp16), 16B-granule XOR swizzle.
// byte addr = r*512 + (((c>>3) ^ (r&31)) * 16) + (c&7)*2
__device__ __forceinline__ int lds_idx(int r, int c) {
  return (r << 8) + ((((c >> 3) ^ (r & 31)) << 3) | (c & 7));
}

// B-fragments for the 272x256 augmented weight, this wave's column n.
// rows 0..255 = M (U or W1), 256..263 = Wx (or 0), 264 = bias, 265..271 = 0.
__device__ __forceinline__ void load_bfrags(half8 bf[17],
                                            const float* __restrict__ M,
                                            const float* __restrict__ Wx,
                                            const float* __restrict__ bias,
                                            int n, int q) {
  #pragma unroll
  for (int kf = 0; kf < 16; ++kf) {
    const int k0 = 16 * kf + 8 * q;
    half8 v;
    #pragma unroll
    for (int j = 0; j < 8; ++j)
      v[j] = (h16)M[(size_t)(k0 + j) * C_DIM + n];
    bf[kf] = v;
  }
  half8 v;
  #pragma unroll
  for (int j = 0; j < 8; ++j) v[j] = (h16)0.f;
  if (q == 0) {
    if (Wx) {
      #pragma unroll
      for (int j = 0; j < 8; ++j) v[j] = (h16)Wx[j * C_DIM + n];
    }
  } else {
    v[0] = (h16)bias[n];  // k=264 pairs with A-side constant 1.0
  }
  bf[16] = v;
}

__global__ __launch_bounds__(512, 4)
void rnn_fused(const float* __restrict__ x, const float* __restrict__ W,
               const float* __restrict__ U, const float* __restrict__ b,
               const float* __restrict__ W1, const float* __restrict__ b1,
               float* __restrict__ out) {
  __shared__ alignas(16) h16 hbuf[2][64 * 256];  // 2 x 32 KB

  const int tid = threadIdx.x;
  const int lane = tid & 63;
  const int wave = tid >> 6;        // 0..7, owns cols [32w, 32w+32)
  const int l31 = lane & 31;
  const int q = lane >> 5;
  const int row0 = blockIdx.x << 6; // 64 batch rows per block
  const int n = (wave << 5) + l31;  // this lane's output column

  half8 bf[17];
  load_bfrags(bf, U, W, b, n, q);

  int buf = 0;
  #pragma unroll 1
  for (int s = 0; s < T_STEPS; ++s) {
    // augmented A fragment: q==0 lanes carry x_t (fp32->fp16), q==1 carry
    // [1,0..] for the bias slot. Issue global loads before the barrier.
    const int t = T_STEPS - 1 - s;  // go_backwards
    half8 xa[2];
    #pragma unroll
    for (int mf = 0; mf < 2; ++mf) {
      half8 v;
      if (q == 0) {
        const float* xp = x + (size_t)(row0 + 32 * mf + l31) * (T_STEPS * F_IN)
                            + (size_t)t * F_IN;
        const f32x4* xp4 = (const f32x4*)xp;
        const f32x4 lo = xp4[0], hi = xp4[1];
        v[0] = (h16)lo[0]; v[1] = (h16)lo[1]; v[2] = (h16)lo[2]; v[3] = (h16)lo[3];
        v[4] = (h16)hi[0]; v[5] = (h16)hi[1]; v[6] = (h16)hi[2]; v[7] = (h16)hi[3];
      } else {
        #pragma unroll
        for (int j = 0; j < 8; ++j) v[j] = (h16)0.f;
        v[0] = (h16)1.f;
      }
      xa[mf] = v;
    }

    __syncthreads();  // h(s-1) writes visible in hbuf[buf]

    f32x16 acc[2];
    #pragma unroll
    for (int mf = 0; mf < 2; ++mf)
      acc[mf] = __builtin_amdgcn_mfma_f32_32x32x16_f16(
          xa[mf], bf[16], (f32x16)(0.f), 0, 0, 0);

    if (s > 0) {  // h_0 = 0
      const h16* hb = hbuf[buf];
      const int c0 = 8 * q;
      #pragma unroll
      for (int kf = 0; kf < 16; ++kf) {
        #pragma unroll
        for (int mf = 0; mf < 2; ++mf) {
          const half8 a =
              *(const half8*)&hb[lds_idx(32 * mf + l31, 16 * kf + c0)];
          acc[mf] = __builtin_amdgcn_mfma_f32_32x32x16_f16(
              a, bf[kf], acc[mf], 0, 0, 0);
        }
      }
    }

    // epilogue: relu -> fp16 -> other LDS buffer (32 ds_write_b16/wave)
    h16* hn = hbuf[buf ^ 1];
    #pragma unroll
    for (int mf = 0; mf < 2; ++mf) {
      #pragma unroll
      for (int reg = 0; reg < 16; ++reg) {
        const float v = fmaxf(acc[mf][reg], 0.f);
        const int rr = (reg & 3) + ((reg >> 2) << 3) + (q << 2) + (mf << 5);
        hn[lds_idx(rr, n)] = (h16)v;
      }
    }
    buf ^= 1;
  }

  // final Dense(256, relu): same GEMM step with W1/b1, x rows zeroed
  load_bfrags(bf, W1, nullptr, b1, n, q);
  half8 xa;
  #pragma unroll
  for (int j = 0; j < 8; ++j) xa[j] = (h16)0.f;
  if (q == 1) xa[0] = (h16)1.f;

  __syncthreads();

  f32x16 acc[2];
  #pragma unroll
  for (int mf = 0; mf < 2; ++mf)
    acc[mf] = __builtin_amdgcn_mfma_f32_32x32x16_f16(
        xa, bf[16], (f32x16)(0.f), 0, 0, 0);

  {
    const h16* hb = hbuf[buf];
    const int c0 = 8 * q;
    #pragma unroll
    for (int kf = 0; kf < 16; ++kf) {
      #pragma unroll
      for (int mf = 0; mf < 2; ++mf) {
        const half8 a =
            *(const half8*)&hb[lds_idx(32 * mf + l31, 16 * kf + c0)];
        acc[mf] = __builtin_amdgcn_mfma_f32_32x32x16_f16(
            a, bf[kf], acc[mf], 0, 0, 0);
      }
    }
  }

  #pragma unroll
  for (int mf = 0; mf < 2; ++mf) {
    #pragma unroll
    for (int reg = 0; reg < 16; ++reg) {
      const float v = fmaxf(acc[mf][reg], 0.f);
      const int rr = (reg & 3) + ((reg >> 2) << 3) + (q << 2) + (mf << 5);
      out[(size_t)(row0 + rr) * C_DIM + n] = v;
    }
  }
}

extern "C" void kernel_launch(void* const* d_in, const int* in_sizes, int n_in,
                              void* d_out, int out_size, void* d_ws, size_t ws_size,
                              hipStream_t stream) {
  const float* x  = (const float*)d_in[0];
  const float* W  = (const float*)d_in[1];
  const float* U  = (const float*)d_in[2];
  const float* b  = (const float*)d_in[3];
  const float* W1 = (const float*)d_in[4];
  const float* b1 = (const float*)d_in[5];
  float* out = (float*)d_out;

  rnn_fused<<<B_ROWS / 64, 512, 0, stream>>>(x, W, U, b, W1, b1, out);
}

// Round 3
// 1316.417 us; speedup vs baseline: 1.3360x; 1.3360x over previous
//
#include <hip/hip_runtime.h>

// RNNBlock: h_t = relu(x_t @ W + h_{t-1} @ U + b) over reversed T, then
// out = relu(h @ W1 + b1).  B=65536, T=79, F=8, C=DW=256.
//
// R3: block = 256 threads (4 waves) x 64 batch rows; each wave owns 64 output
// channels (nf=2) -> each 16B LDS A-read feeds 2 MFMAs (A-replication 4x, was
// 8x in R2). Weights register-resident: bf[17][2] = 136 VGPRs; total ~220.
// CRITICAL FIX from R1/R2 post-mortem: __launch_bounds__ 2nd arg is only a
// MINIMUM waves/EU -- the allocator targeted 8 waves/EU and spilled the whole
// weight file to scratch (R2: VGPR_Count=64, FETCH 2.8GB of scratch thrash).
// amdgpu_waves_per_eu(2,2) pins the occupancy target -> 256-reg budget.
// LDS h-writes packed to b32 via DPP quad_perm (VALU pipe) to halve DS write
// instruction count.
//
// MFMA v_mfma_f32_32x32x16_f16 layouts (learn_hip verified):
//   A[m][k]: m = lane&31, k = 8*(lane>>5) + j
//   B[k][n]: k = 8*(lane>>5) + j, n = lane&31
//   C/D    : col = lane&31, row = (reg&3) + 8*(reg>>2) + 4*(lane>>5)

#define B_ROWS 65536
#define T_STEPS 79
#define F_IN 8
#define C_DIM 256

typedef _Float16 h16;
typedef __attribute__((ext_vector_type(2))) _Float16 half2;
typedef __attribute__((ext_vector_type(8))) _Float16 half8;
typedef __attribute__((ext_vector_type(16))) float f32x16;
typedef __attribute__((ext_vector_type(4))) float f32x4;

// LDS element index for h[r][c] (fp16), 16B-granule XOR swizzle
// (R2 measured SQ_LDS_BANK_CONFLICT = 0 with this layout).
// byte addr = r*512 + (((c>>3) ^ (r&31)) * 16) + (c&7)*2
__device__ __forceinline__ int lds_idx(int r, int c) {
  return (r << 8) + ((((c >> 3) ^ (r & 31)) << 3) | (c & 7));
}

// lane^1 exchange on the VALU pipe (DPP quad_perm [1,0,3,2]) -- keeps the
// epilogue transpose off the DS pipe (ds_swizzle/bpermute would compete with
// the A-frag reads).
__device__ __forceinline__ float dpp_xor1(float v) {
  int i = __builtin_bit_cast(int, v);
  int r = __builtin_amdgcn_update_dpp(0, i, 0xB1, 0xF, 0xF, false);
  return __builtin_bit_cast(float, r);
}

// B-fragments for the 272x256 augmented weight (rows 0..255 = M (U or W1),
// 256..263 = Wx (or 0), 264 = bias, 265..271 = 0), wave cols [ncb, ncb+64).
__device__ __forceinline__ void load_bfrags(half8 bf[17][2],
                                            const float* __restrict__ M,
                                            const float* __restrict__ Wx,
                                            const float* __restrict__ bias,
                                            int ncb, int l31, int q) {
  #pragma unroll
  for (int kf = 0; kf < 16; ++kf) {
    const int k0 = 16 * kf + 8 * q;
    #pragma unroll
    for (int nf = 0; nf < 2; ++nf) {
      const int n = ncb + 32 * nf + l31;
      half8 v;
      #pragma unroll
      for (int j = 0; j < 8; ++j)
        v[j] = (h16)M[(size_t)(k0 + j) * C_DIM + n];
      bf[kf][nf] = v;
    }
  }
  #pragma unroll
  for (int nf = 0; nf < 2; ++nf) {
    const int n = ncb + 32 * nf + l31;
    half8 v;
    #pragma unroll
    for (int j = 0; j < 8; ++j) v[j] = (h16)0.f;
    if (q == 0) {
      if (Wx) {
        #pragma unroll
        for (int j = 0; j < 8; ++j) v[j] = (h16)Wx[j * C_DIM + n];
      }
    } else {
      v[0] = (h16)bias[n];  // k=264 pairs with A-side constant 1.0
    }
    bf[16][nf] = v;
  }
}

__global__ __launch_bounds__(256)
__attribute__((amdgpu_waves_per_eu(2, 2)))
void rnn_fused(const float* __restrict__ x, const float* __restrict__ W,
               const float* __restrict__ U, const float* __restrict__ b,
               const float* __restrict__ W1, const float* __restrict__ b1,
               float* __restrict__ out) {
  __shared__ alignas(16) h16 hbuf[2][64 * 256];  // 2 x 32 KB

  const int tid = threadIdx.x;
  const int lane = tid & 63;
  const int wave = tid >> 6;        // 0..3, owns cols [64w, 64w+64)
  const int l31 = lane & 31;
  const int q = lane >> 5;
  const int row0 = blockIdx.x << 6; // 64 batch rows per block
  const int ncb = wave << 6;

  half8 bf[17][2];
  load_bfrags(bf, U, W, b, ncb, l31, q);

  int buf = 0;
  #pragma unroll 1
  for (int s = 0; s < T_STEPS; ++s) {
    // augmented A fragment: q==0 lanes carry x_t (fp32->fp16), q==1 carry
    // [1,0..] for the bias slot. Global loads issued before the barrier.
    const int t = T_STEPS - 1 - s;  // go_backwards
    half8 xa[2];
    #pragma unroll
    for (int mf = 0; mf < 2; ++mf) {
      half8 v;
      if (q == 0) {
        const float* xp = x + (size_t)(row0 + 32 * mf + l31) * (T_STEPS * F_IN)
                            + (size_t)t * F_IN;
        const f32x4* xp4 = (const f32x4*)xp;
        const f32x4 lo = xp4[0], hi = xp4[1];
        v[0] = (h16)lo[0]; v[1] = (h16)lo[1]; v[2] = (h16)lo[2]; v[3] = (h16)lo[3];
        v[4] = (h16)hi[0]; v[5] = (h16)hi[1]; v[6] = (h16)hi[2]; v[7] = (h16)hi[3];
      } else {
        #pragma unroll
        for (int j = 0; j < 8; ++j) v[j] = (h16)0.f;
        v[0] = (h16)1.f;
      }
      xa[mf] = v;
    }

    __syncthreads();  // h(s-1) writes visible in hbuf[buf]

    f32x16 acc[2][2];
    #pragma unroll
    for (int mf = 0; mf < 2; ++mf)
      #pragma unroll
      for (int nf = 0; nf < 2; ++nf)
        acc[mf][nf] = __builtin_amdgcn_mfma_f32_32x32x16_f16(
            xa[mf], bf[16][nf], (f32x16)(0.f), 0, 0, 0);

    if (s > 0) {  // h_0 = 0
      const h16* hb = hbuf[buf];
      const int c0 = 8 * q;
      #pragma unroll
      for (int kf = 0; kf < 16; ++kf) {
        #pragma unroll
        for (int mf = 0; mf < 2; ++mf) {
          const half8 a =
              *(const half8*)&hb[lds_idx(32 * mf + l31, 16 * kf + c0)];
          #pragma unroll
          for (int nf = 0; nf < 2; ++nf)
            acc[mf][nf] = __builtin_amdgcn_mfma_f32_32x32x16_f16(
                a, bf[kf][nf], acc[mf][nf], 0, 0, 0);
        }
      }
    }

    // epilogue: relu -> fp16 pairs (DPP lane^1 exchange) -> b32 LDS writes
    h16* hn = hbuf[buf ^ 1];
    const int odd = l31 & 1;
    #pragma unroll
    for (int mf = 0; mf < 2; ++mf) {
      #pragma unroll
      for (int nf = 0; nf < 2; ++nf) {
        const int cc = ncb + (nf << 5) + (l31 & ~1);
        #pragma unroll
        for (int rp = 0; rp < 8; ++rp) {
          const int r = 2 * rp;
          const float va = fmaxf(acc[mf][nf][r], 0.f);
          const float vb = fmaxf(acc[mf][nf][r + 1], 0.f);
          const float na = dpp_xor1(va);   // partner's row-Ra value
          const float nb = dpp_xor1(vb);   // partner's row-Rb value
          // even lane -> row Ra cols (l31, l31+1); odd -> row Rb cols (l31-1, l31)
          const float lo = odd ? nb : va;
          const float hi = odd ? vb : na;
          const half2 pk = {(h16)lo, (h16)hi};
          const int rr = (r & 3) + ((r >> 2) << 3) + (q << 2) + (mf << 5) + odd;
          *(half2*)&hn[lds_idx(rr, cc)] = pk;
        }
      }
    }
    buf ^= 1;
  }

  // final Dense(256, relu): same GEMM step with W1/b1, x rows zeroed
  load_bfrags(bf, W1, nullptr, b1, ncb, l31, q);
  half8 xa;
  #pragma unroll
  for (int j = 0; j < 8; ++j) xa[j] = (h16)0.f;
  if (q == 1) xa[0] = (h16)1.f;

  __syncthreads();

  f32x16 acc[2][2];
  #pragma unroll
  for (int mf = 0; mf < 2; ++mf)
    #pragma unroll
    for (int nf = 0; nf < 2; ++nf)
      acc[mf][nf] = __builtin_amdgcn_mfma_f32_32x32x16_f16(
          xa, bf[16][nf], (f32x16)(0.f), 0, 0, 0);

  {
    const h16* hb = hbuf[buf];
    const int c0 = 8 * q;
    #pragma unroll
    for (int kf = 0; kf < 16; ++kf) {
      #pragma unroll
      for (int mf = 0; mf < 2; ++mf) {
        const half8 a =
            *(const half8*)&hb[lds_idx(32 * mf + l31, 16 * kf + c0)];
        #pragma unroll
        for (int nf = 0; nf < 2; ++nf)
          acc[mf][nf] = __builtin_amdgcn_mfma_f32_32x32x16_f16(
              a, bf[kf][nf], acc[mf][nf], 0, 0, 0);
      }
    }
  }

  #pragma unroll
  for (int mf = 0; mf < 2; ++mf) {
    #pragma unroll
    for (int nf = 0; nf < 2; ++nf) {
      #pragma unroll
      for (int reg = 0; reg < 16; ++reg) {
        const float v = fmaxf(acc[mf][nf][reg], 0.f);
        const int rr = (reg & 3) + ((reg >> 2) << 3) + (q << 2) + (mf << 5);
        const int cc = ncb + (nf << 5) + l31;
        out[(size_t)(row0 + rr) * C_DIM + cc] = v;
      }
    }
  }
}

extern "C" void kernel_launch(void* const* d_in, const int* in_sizes, int n_in,
                              void* d_out, int out_size, void* d_ws, size_t ws_size,
                              hipStream_t stream) {
  const float* x  = (const float*)d_in[0];
  const float* W  = (const float*)d_in[1];
  const float* U  = (const float*)d_in[2];
  const float* b  = (const float*)d_in[3];
  const float* W1 = (const float*)d_in[4];
  const float* b1 = (const float*)d_in[5];
  float* out = (float*)d_out;

  rnn_fused<<<B_ROWS / 64, 256, 0, stream>>>(x, W, U, b, W1, b1, out);
}